// Round 1
// 71.548 us; speedup vs baseline: 1.0522x; 1.0522x over previous
//
#include <hip/hip_runtime.h>
#include <math.h>

#define B_SZ   256
#define T_SZ   50
#define N_OBS  8192
#define N_KC   50

using f32x4 = __attribute__((ext_vector_type(4))) float;

// Broadcast lane l's float to all lanes as a wave-uniform (SGPR) value.
// readlane has no LDS traffic -> no lgkmcnt latency on the scan's path.
__device__ __forceinline__ float rlf(float v, int l) {
    return __uint_as_float((unsigned)__builtin_amdgcn_readlane((int)__float_as_uint(v), l));
}

// ---------------------------------------------------------------------------
// K1: assign8[i] = column of the single 1.0 in one-hot row A[i,:], as uint8
//     (N_KC=50 < 256). A is scanned FLAT with float4 (fully coalesced,
//     1.6 MB); each one-hot hit produces one scattered byte store.
// ---------------------------------------------------------------------------
__global__ void __launch_bounds__(256) k_assign(
        const float* __restrict__ A,
        unsigned char* __restrict__ assign8) {
    const int idx = blockIdx.x * 256 + threadIdx.x;   // float4 index
    // N_OBS*N_KC = 409600 floats = 102400 float4 -> exactly 400 blocks.
    const float4 v = ((const float4*)A)[idx];
    const int e = idx * 4;
    if (v.x > 0.5f) assign8[(e + 0) / N_KC] = (unsigned char)((e + 0) % N_KC);
    if (v.y > 0.5f) assign8[(e + 1) / N_KC] = (unsigned char)((e + 1) % N_KC);
    if (v.z > 0.5f) assign8[(e + 2) / N_KC] = (unsigned char)((e + 2) % N_KC);
    if (v.w > 0.5f) assign8[(e + 3) / N_KC] = (unsigned char)((e + 3) % N_KC);
}

// ---------------------------------------------------------------------------
// K2: one 512-thread block per batch element, fused scan + expand.
//     Scan (wave 0): the BKT update at step t touches ONLY state[ka_t],
//     which lane ka_t already owns -> the loop-carried dependency is a
//     pure-VALU chain (no cross-lane op): mul||fma -> rcp -> mul -> fma ->
//     cndmask, ~30 cy/step. Per-step constants broadcast via v_readlane
//     (uniform t, no DS). The one remaining bpermute (cs = shfl(st, kc_t),
//     feeds only pc, not the recurrence) is software-pipelined: issued at
//     step t, consumed at step t+1, hiding its ~100 cy latency.
// ---------------------------------------------------------------------------
__global__ void __launch_bounds__(512) k_scan_expand(
        const int*   __restrict__ prev_kc,
        const int*   __restrict__ curr_kc,
        const float* __restrict__ prev_corr,
        const unsigned char* __restrict__ assign8,
        const float* __restrict__ kc_logits,
        float* __restrict__ probs_out,    // [B][T]
        float* __restrict__ state_out) {  // [B][N_OBS]
    const int b    = blockIdx.x;
    const int tid  = threadIdx.x;        // 0..511
    const int lane = tid & 63;
    const int wave = tid >> 6;

    __shared__ float s_probs[N_KC * 5 + 6];
    __shared__ float s_state[64];

    for (int i = tid; i < N_KC * 5; i += 512) {
        float x = kc_logits[i];
        s_probs[i] = __builtin_amdgcn_rcpf(1.0f + __expf(-x));
    }

    // Prefetch this thread's expand indices NOW: 4 dwords, each packing 4
    // uint8 assign values; independent of the scan, complete behind it.
    const unsigned int* a32 = (const unsigned int*)assign8;
    unsigned int pa[4];
    #pragma unroll
    for (int k = 0; k < 4; ++k) pa[k] = a32[tid + k * 512];

    __syncthreads();

    if (wave == 0) {
        // Per-step constants: lane t (t < T) holds the values for timestep t.
        //   po0/po1 : p_out components (pow reduced to select, corr in {0,1})
        //   pl      : p_learn
        //   cf      : 1 - p_forget - p_learn   (pred = fma(cf, filt, pl))
        //   c2/dc   : cp2 and cp3-cp2          (pc = fma(dc, cs, c2))
        int   ka = 0, kc = 0;
        float po0 = 0.f, po1 = 0.f, pl = 0.f, cf = 0.f, c2 = 0.f, dc = 0.f;
        if (lane < T_SZ) {
            int   pk   = prev_kc[b * T_SZ + lane];
            int   ck   = curr_kc[b * T_SZ + lane];
            float corr = prev_corr[b * T_SZ + lane];
            ka = assign8[pk];
            kc = assign8[ck];
            float pp0 = s_probs[ka * 5 + 0];
            float pp1 = s_probs[ka * 5 + 1];
            float pp2 = s_probs[ka * 5 + 2];
            float pp3 = s_probs[ka * 5 + 3];
            bool c = corr > 0.5f;
            po0 = c ? pp2 : 1.0f - pp2;
            po1 = c ? pp3 : 1.0f - pp3;
            pl  = pp0;
            cf  = 1.0f - pp1 - pp0;
            c2  = s_probs[kc * 5 + 2];
            dc  = s_probs[kc * 5 + 3] - c2;
        }

        // Initial per-KC state: lane k holds sigmoid(kc_logits[k,4]).
        float st = (lane < N_KC) ? s_probs[lane * 5 + 4] : 0.0f;

        float pc_mine = 0.0f;

        // t = 0: prediction only, no state update. Issue the bpermute now;
        // its result is consumed at the end of iteration t = 1.
        int   kc0     = __builtin_amdgcn_readlane(kc, 0);
        float cs_prev = __shfl(st, kc0);
        float c2p     = rlf(c2, 0);
        float dcp     = rlf(dc, 0);
        int   tprev   = 0;

        for (int t = 1; t < T_SZ; ++t) {
            // Wave-uniform per-step constants (readlane: no DS latency).
            int   ka_t  = __builtin_amdgcn_readlane(ka, t);
            float po0_t = rlf(po0, t);
            float po1_t = rlf(po1, t);
            float pl_t  = rlf(pl, t);
            float cf_t  = rlf(cf, t);
            int   kc_t  = __builtin_amdgcn_readlane(kc, t);
            float c2_t  = rlf(c2, t);
            float dc_t  = rlf(dc, t);

            // Local update: lane ka_t owns state[ka_t]; no shuffle needed.
            // Carried chain: st -> (num||den) -> rcp -> mul -> fma -> cndmask
            float ss   = st;
            float num  = po1_t * ss;
            float den  = __builtin_fmaf(po1_t - po0_t, ss, po0_t);
            float filt = num * __builtin_amdgcn_rcpf(den);
            float pred = __builtin_fmaf(cf_t, filt, pl_t);
            if (lane == ka_t) st = pred;

            // Issue this step's prediction gather (off the carried path).
            float cs_t = __shfl(st, kc_t);

            // Consume the PREVIOUS step's gather (latency fully hidden).
            float pc = __builtin_fmaf(dcp, cs_prev, c2p);
            if (lane == tprev) pc_mine = pc;

            cs_prev = cs_t;
            c2p = c2_t;
            dcp = dc_t;
            tprev = t;
        }
        // Final prediction (t = T-1).
        {
            float pc = __builtin_fmaf(dcp, cs_prev, c2p);
            if (lane == T_SZ - 1) pc_mine = pc;
        }

        if (lane < T_SZ) probs_out[b * T_SZ + lane] = pc_mine;
        s_state[lane] = st;
    }
    __syncthreads();

    // Expand: state_out[b][j] = s_state[assign[j]].
    // Unpack 4 uint8 indices per dword, LDS gather, coalesced float4 store.
    f32x4* outp = (f32x4*)(state_out + (long)b * N_OBS);
    #pragma unroll
    for (int k = 0; k < 4; ++k) {
        const int i = tid + k * 512;
        const unsigned int w = pa[k];
        f32x4 v;
        v.x = s_state[w & 0xffu];
        v.y = s_state[(w >> 8)  & 0xffu];
        v.z = s_state[(w >> 16) & 0xffu];
        v.w = s_state[(w >> 24) & 0xffu];
        __builtin_nontemporal_store(v, &outp[i]);
    }
}

extern "C" void kernel_launch(void* const* d_in, const int* in_sizes, int n_in,
                              void* d_out, int out_size, void* d_ws, size_t ws_size,
                              hipStream_t stream) {
    const int*   prev_kc   = (const int*)  d_in[0];
    const int*   curr_kc   = (const int*)  d_in[1];
    const float* prev_corr = (const float*)d_in[2];
    const float* kc_logits = (const float*)d_in[3];
    const float* A         = (const float*)d_in[4];

    float* probs_out = (float*)d_out;                 // B*T
    float* state_out = (float*)d_out + B_SZ * T_SZ;   // B*N_OBS

    unsigned char* assign8 = (unsigned char*)d_ws;    // 8 KB of workspace

    k_assign<<<(N_OBS * N_KC / 4) / 256, 256, 0, stream>>>(A, assign8);
    k_scan_expand<<<B_SZ, 512, 0, stream>>>(prev_kc, curr_kc, prev_corr,
                                            assign8, kc_logits,
                                            probs_out, state_out);
}

// Round 2
// 69.923 us; speedup vs baseline: 1.0766x; 1.0232x over previous
//
#include <hip/hip_runtime.h>
#include <math.h>

#define B_SZ   256
#define T_SZ   50
#define N_OBS  8192
#define N_KC   50

using f32x4 = __attribute__((ext_vector_type(4))) float;

// Broadcast lane l's float to all lanes as a wave-uniform value via
// v_readlane (no LDS traffic, no lgkmcnt). l may be an immediate or a
// wave-uniform runtime value.
__device__ __forceinline__ float rlf(float v, int l) {
    return __uint_as_float((unsigned)__builtin_amdgcn_readlane((int)__float_as_uint(v), l));
}

// ---------------------------------------------------------------------------
// K1: assign8[i] = column of the single 1.0 in one-hot row A[i,:], as uint8
//     (N_KC=50 < 256). A is scanned FLAT with float4 (fully coalesced,
//     1.6 MB); each one-hot hit produces one scattered byte store.
// ---------------------------------------------------------------------------
__global__ void __launch_bounds__(256) k_assign(
        const float* __restrict__ A,
        unsigned char* __restrict__ assign8) {
    const int idx = blockIdx.x * 256 + threadIdx.x;   // float4 index
    // N_OBS*N_KC = 409600 floats = 102400 float4 -> exactly 400 blocks.
    const float4 v = ((const float4*)A)[idx];
    const int e = idx * 4;
    if (v.x > 0.5f) assign8[(e + 0) / N_KC] = (unsigned char)((e + 0) % N_KC);
    if (v.y > 0.5f) assign8[(e + 1) / N_KC] = (unsigned char)((e + 1) % N_KC);
    if (v.z > 0.5f) assign8[(e + 2) / N_KC] = (unsigned char)((e + 2) % N_KC);
    if (v.w > 0.5f) assign8[(e + 3) / N_KC] = (unsigned char)((e + 3) % N_KC);
}

// ---------------------------------------------------------------------------
// K2: one 512-thread block per batch element, fused scan + expand.
//     Scan (wave 0): pure-VALU serial recurrence. The state update at step t
//     touches ONLY state[ka_t], owned by lane ka_t -> carried chain is
//     den=fma -> rcp -> fma -> cndmask (no cross-lane op). ALL broadcasts,
//     including the post-update gather cs = state[kc_t], use v_readlane
//     (kc_t is wave-uniform) -> zero DS ops in the scan. T-loop fully
//     unrolled so next-step readlanes schedule under this step's chain.
//     Input loads are issued at kernel entry so their HBM-cold latency
//     (caches are flushed by the harness's 256 MiB poison) hides under the
//     sigmoid/LDS phase.
// ---------------------------------------------------------------------------
__global__ void __launch_bounds__(512) k_scan_expand(
        const int*   __restrict__ prev_kc,
        const int*   __restrict__ curr_kc,
        const float* __restrict__ prev_corr,
        const unsigned char* __restrict__ assign8,
        const float* __restrict__ kc_logits,
        float* __restrict__ probs_out,    // [B][T]
        float* __restrict__ state_out) {  // [B][N_OBS]
    const int b    = blockIdx.x;
    const int tid  = threadIdx.x;        // 0..511
    const int lane = tid & 63;
    const int wave = tid >> 6;

    __shared__ float s_probs[N_KC * 5 + 6];
    __shared__ float s_state[64];

    // Issue the scan's input loads FIRST (HBM-cold after the workspace
    // poison); they complete behind the sigmoid compute below.
    const bool scanlane = (wave == 0) && (lane < T_SZ);
    int pk = 0, ck = 0;
    float corr = 0.0f;
    if (scanlane) {
        pk   = prev_kc[b * T_SZ + lane];
        ck   = curr_kc[b * T_SZ + lane];
        corr = prev_corr[b * T_SZ + lane];
    }

    for (int i = tid; i < N_KC * 5; i += 512) {
        float x = kc_logits[i];
        s_probs[i] = __builtin_amdgcn_rcpf(1.0f + __expf(-x));
    }

    // Dependent gathers: issue as soon as pk/ck are back.
    int ka = 0, kc = 0;
    if (scanlane) {
        ka = assign8[pk];
        kc = assign8[ck];
    }

    // Prefetch this thread's expand indices: 4 dwords, each packing 4 uint8
    // assign values; independent of the scan, complete behind it.
    const unsigned int* a32 = (const unsigned int*)assign8;
    unsigned int pa[4];
    #pragma unroll
    for (int k = 0; k < 4; ++k) pa[k] = a32[tid + k * 512];

    __syncthreads();

    if (wave == 0) {
        // Per-step constants: lane t (t < T) holds the values for timestep t.
        //   po0   : p_out[:,0]        (pow reduced to select, corr in {0,1})
        //   dp    : po1 - po0         (den = fma(dp, ss, po0))
        //   cfp1  : (1-pf-pl) * po1   (pred = fma(cfp1*ss, rcp(den), pl))
        //   pl    : p_learn
        //   c2/dc : cp2, cp3-cp2      (pc = fma(dc, cs, c2))
        float po0 = 0.f, dp = 0.f, cfp1 = 0.f, pl = 0.f, c2 = 0.f, dc = 0.f;
        if (scanlane) {
            float pp0 = s_probs[ka * 5 + 0];
            float pp1 = s_probs[ka * 5 + 1];
            float pp2 = s_probs[ka * 5 + 2];
            float pp3 = s_probs[ka * 5 + 3];
            bool c = corr > 0.5f;
            po0 = c ? pp2 : 1.0f - pp2;
            float po1 = c ? pp3 : 1.0f - pp3;
            dp   = po1 - po0;
            pl   = pp0;
            cfp1 = (1.0f - pp1 - pp0) * po1;
            c2   = s_probs[kc * 5 + 2];
            dc   = s_probs[kc * 5 + 3] - c2;
        }

        // Initial per-KC state: lane k holds sigmoid(kc_logits[k,4]).
        float st = (lane < N_KC) ? s_probs[lane * 5 + 4] : 0.0f;

        float pc_mine = 0.0f;

        // t = 0: prediction only, no state update.
        {
            int   kc0 = __builtin_amdgcn_readlane(kc, 0);
            float cs  = rlf(st, kc0);
            float pc  = __builtin_fmaf(rlf(dc, 0), cs, rlf(c2, 0));
            if (lane == 0) pc_mine = pc;
        }

        // t = 1..T-1: serial recurrence, fully unrolled (lane operands of
        // readlane become immediates; independent broadcasts for step t+1
        // schedule under step t's fma->rcp->fma->cndmask chain).
        #pragma unroll
        for (int t = 1; t < T_SZ; ++t) {
            int   ka_t   = __builtin_amdgcn_readlane(ka, t);
            float po0_t  = rlf(po0, t);
            float dp_t   = rlf(dp, t);
            float cfp1_t = rlf(cfp1, t);
            float pl_t   = rlf(pl, t);
            int   kc_t   = __builtin_amdgcn_readlane(kc, t);
            float c2_t   = rlf(c2, t);
            float dc_t   = rlf(dc, t);

            // Local update: lane ka_t owns state[ka_t]; no cross-lane op.
            float ss   = st;
            float t1   = cfp1_t * ss;                       // off-chain
            float den  = __builtin_fmaf(dp_t, ss, po0_t);
            float pred = __builtin_fmaf(t1, __builtin_amdgcn_rcpf(den), pl_t);
            if (lane == ka_t) st = pred;

            // Prediction gather: kc_t is wave-uniform -> readlane, no DS.
            float cs = rlf(st, kc_t);
            float pc = __builtin_fmaf(dc_t, cs, c2_t);
            if (lane == t) pc_mine = pc;
        }

        if (lane < T_SZ) probs_out[b * T_SZ + lane] = pc_mine;
        s_state[lane] = st;
    }
    __syncthreads();

    // Expand: state_out[b][j] = s_state[assign[j]].
    // Unpack 4 uint8 indices per dword, LDS gather, coalesced float4 store.
    f32x4* outp = (f32x4*)(state_out + (long)b * N_OBS);
    #pragma unroll
    for (int k = 0; k < 4; ++k) {
        const int i = tid + k * 512;
        const unsigned int w = pa[k];
        f32x4 v;
        v.x = s_state[w & 0xffu];
        v.y = s_state[(w >> 8)  & 0xffu];
        v.z = s_state[(w >> 16) & 0xffu];
        v.w = s_state[(w >> 24) & 0xffu];
        __builtin_nontemporal_store(v, &outp[i]);
    }
}

extern "C" void kernel_launch(void* const* d_in, const int* in_sizes, int n_in,
                              void* d_out, int out_size, void* d_ws, size_t ws_size,
                              hipStream_t stream) {
    const int*   prev_kc   = (const int*)  d_in[0];
    const int*   curr_kc   = (const int*)  d_in[1];
    const float* prev_corr = (const float*)d_in[2];
    const float* kc_logits = (const float*)d_in[3];
    const float* A         = (const float*)d_in[4];

    float* probs_out = (float*)d_out;                 // B*T
    float* state_out = (float*)d_out + B_SZ * T_SZ;   // B*N_OBS

    unsigned char* assign8 = (unsigned char*)d_ws;    // 8 KB of workspace

    k_assign<<<(N_OBS * N_KC / 4) / 256, 256, 0, stream>>>(A, assign8);
    k_scan_expand<<<B_SZ, 512, 0, stream>>>(prev_kc, curr_kc, prev_corr,
                                            assign8, kc_logits,
                                            probs_out, state_out);
}